// Round 9
// baseline (251.035 us; speedup 1.0000x reference)
//
#include <hip/hip_runtime.h>

#define DFEAT 64
#define SBSH 10
#define SBN 1024                  // nodes per superbucket
#define NSB 98                    // ceil(100000/1024)
#define ETILE 4096
#define PACKSH 17
#define SRCMASK 0x1FFFF

typedef __bf16 bf16x8 __attribute__((ext_vector_type(8)));
typedef float f32x4 __attribute__((ext_vector_type(4)));

__device__ __forceinline__ unsigned bf16_rne(float v) {
    unsigned bits = __float_as_uint(v);
    return (bits + 0x7FFFu + ((bits >> 16) & 1u)) >> 16;
}

// ---- per-tile superbucket histogram: plain stores, no global atomics ----
__global__ __launch_bounds__(512) void bhist_kernel(const int* __restrict__ dst,
                                                    int n_edges,
                                                    int* __restrict__ counts) {
    __shared__ int lh[NSB];
    int t = threadIdx.x;
    if (t < NSB) lh[t] = 0;
    __syncthreads();
    int s0 = blockIdx.x * ETILE;
    int s1 = s0 + ETILE; if (s1 > n_edges) s1 = n_edges;
    for (int e = s0 + t; e < s1; e += 512)
        atomicAdd(&lh[dst[e] >> SBSH], 1);
    __syncthreads();
    if (t < NSB) counts[blockIdx.x * NSB + t] = lh[t];
}

// ---- deterministic base computation: tilebase[t][sb], sbbase[sb] ----
__global__ __launch_bounds__(128) void tscan_kernel(const int* __restrict__ counts,
                                                    int nt,
                                                    int* __restrict__ tilebase,
                                                    int* __restrict__ sbbase) {
    __shared__ int totals[NSB];
    int sb = threadIdx.x;
    if (sb < NSB) {
        int run = 0;
        for (int tt = 0; tt < nt; ++tt) run += counts[tt * NSB + sb];
        totals[sb] = run;
    }
    __syncthreads();
    if (sb == 0) {
        int run = 0;
        for (int i = 0; i < NSB; ++i) { int c = totals[i]; totals[i] = run; run += c; }
        sbbase[NSB] = run;
    }
    __syncthreads();
    if (sb < NSB) {
        int run = totals[sb];
        sbbase[sb] = run;
        for (int tt = 0; tt < nt; ++tt) {
            tilebase[tt * NSB + sb] = run;
            run += counts[tt * NSB + sb];
        }
    }
}

// ---- partition: single pass, LDS cursors only (no global atomics) ----
__global__ __launch_bounds__(512) void partition_kernel(const int* __restrict__ src,
                                                        const int* __restrict__ dst,
                                                        int n_edges,
                                                        const int* __restrict__ tilebase,
                                                        int* __restrict__ tmp) {
    __shared__ int lcur[NSB];
    int t = threadIdx.x;
    if (t < NSB) lcur[t] = tilebase[blockIdx.x * NSB + t];
    __syncthreads();
    int s0 = blockIdx.x * ETILE;
    int s1 = s0 + ETILE; if (s1 > n_edges) s1 = n_edges;
    for (int e = s0 + t; e < s1; e += 512) {
        int d = dst[e];
        int sb = d >> SBSH;
        int ofs = atomicAdd(&lcur[sb], 1);
        tmp[ofs] = ((d & (SBN - 1)) << PACKSH) | src[e];
    }
}

// ---- per-superbucket counting sort: builds row_ptr + col_src (prescaled <<7) ----
__global__ __launch_bounds__(1024) void bucket_sort_kernel(
    const int* __restrict__ sbbase, const int* __restrict__ tmp,
    int* __restrict__ col_src, int* __restrict__ row_ptr,
    int n_nodes, int n_edges) {
    __shared__ int cnt[SBN];
    __shared__ int scan[SBN];
    int b = blockIdx.x, t = threadIdx.x;
    int gb = sbbase[b], ge = sbbase[b + 1];
    cnt[t] = 0;
    __syncthreads();
    for (int e = gb + t; e < ge; e += 1024)
        atomicAdd(&cnt[((unsigned)tmp[e]) >> PACKSH], 1);
    __syncthreads();
    int v = cnt[t];
    scan[t] = v;
    __syncthreads();
    for (int off = 1; off < 1024; off <<= 1) {
        int x = (t >= off) ? scan[t - off] : 0;
        __syncthreads();
        scan[t] += x;
        __syncthreads();
    }
    int excl = scan[t] - v;
    int node = (b << SBSH) + t;
    if (node < n_nodes) row_ptr[node] = gb + excl;
    cnt[t] = gb + excl;                       // reuse as cursor
    if (b == (int)gridDim.x - 1 && t == 0) row_ptr[n_nodes] = n_edges;
    __syncthreads();
    for (int e = gb + t; e < ge; e += 1024) {
        int pk = tmp[e];
        int pos = atomicAdd(&cnt[((unsigned)pk) >> PACKSH], 1);
        col_src[pos] = (pk & SRCMASK) << 7;   // byte offset of 128B bf16 row
    }
}

// ---- fp32 -> bf16 row conversion (8 elems/thread) ----
__global__ __launch_bounds__(256) void cvt_kernel(const float* __restrict__ x,
                                                  unsigned short* __restrict__ xb,
                                                  int n8) {
    int i = blockIdx.x * 256 + threadIdx.x;
    if (i >= n8) return;
    const float4* xp = (const float4*)x;
    float4 a = xp[2 * i], c = xp[2 * i + 1];
    int4 o;
    o.x = bf16_rne(a.x) | (bf16_rne(a.y) << 16);
    o.y = bf16_rne(a.z) | (bf16_rne(a.w) << 16);
    o.z = bf16_rne(c.x) | (bf16_rne(c.y) << 16);
    o.w = bf16_rne(c.z) | (bf16_rne(c.w) << 16);
    ((int4*)xb)[i] = o;
}

// ---- pack weights (fp32 64x64 k-major) into MFMA B-fragments, hi/lo bf16 split ----
__global__ __launch_bounds__(256) void wpack_kernel(
    const float* __restrict__ Wl1, const float* __restrict__ Wr1,
    const float* __restrict__ Wl2, const float* __restrict__ Wr2,
    unsigned short* __restrict__ wpack) {
    int u = blockIdx.x * 256 + threadIdx.x;   // 2048 units
    if (u >= 2048) return;
    int l = u & 63;
    int ct = (u >> 6) & 3;
    int chunk = (u >> 8) & 1;
    int gemm = (u >> 9) & 1;
    int layer = (u >> 10) & 1;
    const float* W = layer ? (gemm ? Wr2 : Wl2) : (gemm ? Wr1 : Wl1);
    int col = ct * 16 + (l & 15);
    int k0 = chunk * 32 + (l >> 4) * 8;
    unsigned hi[8], lo[8];
#pragma unroll
    for (int j = 0; j < 8; ++j) {
        float w = W[(k0 + j) * DFEAT + col];
        unsigned h = bf16_rne(w);
        float whi = __uint_as_float(h << 16);
        lo[j] = bf16_rne(w - whi);
        hi[j] = h;
    }
    size_t fh = ((((size_t)(layer * 2 + gemm) * 2 + 0) * 2 + chunk) * 4 + ct) * 64 + l;
    size_t fl = ((((size_t)(layer * 2 + gemm) * 2 + 1) * 2 + chunk) * 4 + ct) * 64 + l;
    int4 vh, vl;
    vh.x = hi[0] | (hi[1] << 16); vh.y = hi[2] | (hi[3] << 16);
    vh.z = hi[4] | (hi[5] << 16); vh.w = hi[6] | (hi[7] << 16);
    vl.x = lo[0] | (lo[1] << 16); vl.y = lo[2] | (lo[3] << 16);
    vl.z = lo[4] | (lo[5] << 16); vl.w = lo[6] | (lo[7] << 16);
    ((int4*)wpack)[fh] = vh;
    ((int4*)wpack)[fl] = vl;
}

// ---- gather-mean aggregation (bf16 rows): wave=node, 8 lanes/row, 8 rows/load ----
__global__ __launch_bounds__(512, 8) void agg_kernel(
    const int* __restrict__ row_ptr, const int* __restrict__ col_src,
    const unsigned short* __restrict__ xb, unsigned short* __restrict__ meanb,
    int n_nodes) {
    int w = threadIdx.x >> 6;
    int lane = threadIdx.x & 63;
    int g = lane >> 3;            // row-group 0..7
    int p = lane & 7;             // 16B slot within 128B row
    int node = blockIdx.x * 8 + w;
    if (node >= n_nodes) return;  // no barriers in this kernel

    int start = row_ptr[node];
    int end = row_ptr[node + 1];
    int deg = end - start;

    float acc[8] = {0.f, 0.f, 0.f, 0.f, 0.f, 0.f, 0.f, 0.f};
    const char* xbase = (const char*)xb + p * 16;

    for (int base = start; base < end; base += 64) {
        int m = end - base; if (m > 64) m = 64;
        int soff = col_src[base + (lane < m ? lane : 0)];
        for (int i = 0; i < m; i += 32) {
#pragma unroll
            for (int k = 0; k < 4; ++k) {
                if (i + 8 * k < m) {                       // wave-uniform
                    int n = i + 8 * k + g;
                    int off = __shfl(soff, n < m ? n : 0);
                    float f = (n < m) ? 1.0f : 0.0f;
                    int4 v = *(const int4*)(xbase + off);
                    acc[0] += f * __uint_as_float(((unsigned)v.x) << 16);
                    acc[1] += f * __uint_as_float(((unsigned)v.x) & 0xFFFF0000u);
                    acc[2] += f * __uint_as_float(((unsigned)v.y) << 16);
                    acc[3] += f * __uint_as_float(((unsigned)v.y) & 0xFFFF0000u);
                    acc[4] += f * __uint_as_float(((unsigned)v.z) << 16);
                    acc[5] += f * __uint_as_float(((unsigned)v.z) & 0xFFFF0000u);
                    acc[6] += f * __uint_as_float(((unsigned)v.w) << 16);
                    acc[7] += f * __uint_as_float(((unsigned)v.w) & 0xFFFF0000u);
                }
            }
        }
    }

#pragma unroll
    for (int d = 8; d < 64; d <<= 1) {
#pragma unroll
        for (int e = 0; e < 8; ++e) acc[e] += __shfl_xor(acc[e], d);
    }

    if (g == 0) {
        float inv = (deg > 0) ? 1.0f / (float)deg : 0.0f;
        unsigned u[8];
#pragma unroll
        for (int e = 0; e < 8; ++e) u[e] = bf16_rne(acc[e] * inv);
        int4 o;
        o.x = u[0] | (u[1] << 16);
        o.y = u[2] | (u[3] << 16);
        o.z = u[4] | (u[5] << 16);
        o.w = u[6] | (u[7] << 16);
        *(int4*)((char*)meanb + (size_t)node * 128 + p * 16) = o;
    }
}

// ---- MFMA linear: out[16n x 64] = [A|X] @ [Wl;Wr] + b ; one wave per 16-node tile ----
template <bool RELU, bool OUT_BF16>
__global__ __launch_bounds__(256) void linear_kernel(
    const unsigned short* __restrict__ Ab, const unsigned short* __restrict__ Xb,
    const unsigned short* __restrict__ wpack,   // layer-offset applied by caller
    const float* __restrict__ bias, void* __restrict__ outp,
    int n_nodes, int ntiles) {
    int wave = (blockIdx.x * 256 + threadIdx.x) >> 6;
    if (wave >= ntiles) return;
    int l = threadIdx.x & 63;
    int row16 = l & 15;
    int kq = l >> 4;
    int node0 = wave * 16;

    int arow = node0 + row16;
    if (arow >= n_nodes) arow = n_nodes - 1;
    const char* ap = (const char*)Ab + (size_t)arow * 128 + kq * 16;
    const char* xp = (const char*)Xb + (size_t)arow * 128 + kq * 16;
    bf16x8 aA0 = *(const bf16x8*)ap;
    bf16x8 aA1 = *(const bf16x8*)(ap + 64);
    bf16x8 aX0 = *(const bf16x8*)xp;
    bf16x8 aX1 = *(const bf16x8*)(xp + 64);

    const bf16x8* wp = (const bf16x8*)wpack;
#pragma unroll
    for (int ct = 0; ct < 4; ++ct) {
        float bcol = bias[ct * 16 + row16];
        f32x4 acc = {bcol, bcol, bcol, bcol};
        bf16x8 b000 = wp[0 * 256 + ct * 64 + l];   // A, hi, c0
        bf16x8 b001 = wp[1 * 256 + ct * 64 + l];   // A, hi, c1
        bf16x8 b010 = wp[2 * 256 + ct * 64 + l];   // A, lo, c0
        bf16x8 b011 = wp[3 * 256 + ct * 64 + l];   // A, lo, c1
        bf16x8 b100 = wp[4 * 256 + ct * 64 + l];   // X, hi, c0
        bf16x8 b101 = wp[5 * 256 + ct * 64 + l];   // X, hi, c1
        bf16x8 b110 = wp[6 * 256 + ct * 64 + l];   // X, lo, c0
        bf16x8 b111 = wp[7 * 256 + ct * 64 + l];   // X, lo, c1
        acc = __builtin_amdgcn_mfma_f32_16x16x32_bf16(aA0, b000, acc, 0, 0, 0);
        acc = __builtin_amdgcn_mfma_f32_16x16x32_bf16(aA1, b001, acc, 0, 0, 0);
        acc = __builtin_amdgcn_mfma_f32_16x16x32_bf16(aA0, b010, acc, 0, 0, 0);
        acc = __builtin_amdgcn_mfma_f32_16x16x32_bf16(aA1, b011, acc, 0, 0, 0);
        acc = __builtin_amdgcn_mfma_f32_16x16x32_bf16(aX0, b100, acc, 0, 0, 0);
        acc = __builtin_amdgcn_mfma_f32_16x16x32_bf16(aX1, b101, acc, 0, 0, 0);
        acc = __builtin_amdgcn_mfma_f32_16x16x32_bf16(aX0, b110, acc, 0, 0, 0);
        acc = __builtin_amdgcn_mfma_f32_16x16x32_bf16(aX1, b111, acc, 0, 0, 0);
#pragma unroll
        for (int reg = 0; reg < 4; ++reg) {
            int row = kq * 4 + reg;                // C/D: row=(lane>>4)*4+reg
            int gn = node0 + row;
            if (gn < n_nodes) {
                float v = acc[reg];
                if (RELU) v = fmaxf(v, 0.0f);
                if (OUT_BF16) {
                    ((unsigned short*)outp)[(size_t)gn * DFEAT + ct * 16 + row16] =
                        (unsigned short)bf16_rne(v);
                } else {
                    ((float*)outp)[(size_t)gn * DFEAT + ct * 16 + row16] = v;
                }
            }
        }
    }
}

extern "C" void kernel_launch(void* const* d_in, const int* in_sizes, int n_in,
                              void* d_out, int out_size, void* d_ws, size_t ws_size,
                              hipStream_t stream) {
    const float* x   = (const float*)d_in[0];
    const int*   ei  = (const int*)d_in[1];
    const float* Wl1 = (const float*)d_in[2];
    const float* Wr1 = (const float*)d_in[3];
    const float* b1  = (const float*)d_in[4];
    const float* Wl2 = (const float*)d_in[5];
    const float* Wr2 = (const float*)d_in[6];
    const float* b2  = (const float*)d_in[7];
    float* out = (float*)d_out;

    int n_nodes = in_sizes[0] / DFEAT;   // 100000
    int n_edges = in_sizes[1] / 2;       // 1600000
    const int* src  = ei;
    const int* dstv = ei + n_edges;
    int nt = (n_edges + ETILE - 1) / ETILE;   // 391

    auto align = [](size_t v) { return (v + 255) & ~(size_t)255; };
    char* ws = (char*)d_ws;
    int* counts   = (int*)ws;            ws += align((size_t)nt * NSB * 4);      // 153KB
    int* tilebase = (int*)ws;            ws += align((size_t)nt * NSB * 4);      // 153KB
    int* sbbase   = (int*)ws;            ws += align((NSB + 1) * 4);
    int* row_ptr  = (int*)ws;            ws += align(((size_t)n_nodes + 1) * 4);
    int* col_src  = (int*)ws;            ws += align((size_t)n_edges * 4);       // 6.4MB
    unsigned short* xb    = (unsigned short*)ws; ws += align((size_t)n_nodes * DFEAT * 2);
    unsigned short* hb    = (unsigned short*)ws; ws += align((size_t)n_nodes * DFEAT * 2);
    unsigned short* meanb = (unsigned short*)ws; ws += align((size_t)n_nodes * DFEAT * 2);
    unsigned short* wpack = (unsigned short*)ws; ws += align((size_t)32768);
    int* tmp      = (int*)d_out;         // 6.4MB, dead until linear2 writes out

    bhist_kernel<<<nt, 512, 0, stream>>>(dstv, n_edges, counts);
    tscan_kernel<<<1, 128, 0, stream>>>(counts, nt, tilebase, sbbase);
    partition_kernel<<<nt, 512, 0, stream>>>(src, dstv, n_edges, tilebase, tmp);
    bucket_sort_kernel<<<NSB, 1024, 0, stream>>>(sbbase, tmp, col_src, row_ptr,
                                                 n_nodes, n_edges);

    int n8 = n_nodes * DFEAT / 8;
    cvt_kernel<<<(n8 + 255) / 256, 256, 0, stream>>>(x, xb, n8);
    wpack_kernel<<<8, 256, 0, stream>>>(Wl1, Wr1, Wl2, Wr2, wpack);

    int ntiles = (n_nodes + 15) / 16;    // 6250
    int nb = (n_nodes + 7) / 8;          // 12500
    int lb = (ntiles + 3) / 4;           // 1563 blocks (4 waves each)

    agg_kernel<<<nb, 512, 0, stream>>>(row_ptr, col_src, xb, meanb, n_nodes);
    linear_kernel<true, true><<<lb, 256, 0, stream>>>(meanb, xb, wpack, b1,
                                                      hb, n_nodes, ntiles);
    agg_kernel<<<nb, 512, 0, stream>>>(row_ptr, col_src, hb, meanb, n_nodes);
    linear_kernel<false, false><<<lb, 256, 0, stream>>>(meanb, hb, wpack + 2048 * 8,
                                                        b2, out, n_nodes, ntiles);
}

// Round 10
// 169.618 us; speedup vs baseline: 1.4800x; 1.4800x over previous
//
#include <hip/hip_runtime.h>

#define DFEAT 64
#define SBSH 10
#define SBN 1024                  // nodes per superbucket
#define NSB 98                    // ceil(100000/1024)
#define ETILE 4096
#define PACKSH 17
#define SRCMASK 0x1FFFF

typedef __bf16 bf16x8 __attribute__((ext_vector_type(8)));
typedef float f32x4 __attribute__((ext_vector_type(4)));

__device__ __forceinline__ unsigned bf16_rne(float v) {
    unsigned bits = __float_as_uint(v);
    return (bits + 0x7FFFu + ((bits >> 16) & 1u)) >> 16;
}

// ---- per-tile superbucket histogram: counts[sb][tile] (transposed), no global atomics ----
__global__ __launch_bounds__(512) void bhist_kernel(const int* __restrict__ dst,
                                                    int n_edges, int nt,
                                                    int* __restrict__ counts) {
    __shared__ int lh[NSB];
    int t = threadIdx.x;
    if (t < NSB) lh[t] = 0;
    __syncthreads();
    int s0 = blockIdx.x * ETILE;
    int s1 = s0 + ETILE; if (s1 > n_edges) s1 = n_edges;
    for (int e = s0 + t; e < s1; e += 512)
        atomicAdd(&lh[dst[e] >> SBSH], 1);
    __syncthreads();
    if (t < NSB) counts[t * nt + blockIdx.x] = lh[t];
}

// ---- scan pass 1: per-sb exclusive scan over its nt tile-counts (contiguous) ----
__global__ __launch_bounds__(512) void tscan1_kernel(const int* __restrict__ counts,
                                                     int nt,
                                                     int* __restrict__ tilebase,
                                                     int* __restrict__ sbtot) {
    __shared__ int sdata[512];
    int sb = blockIdx.x, t = threadIdx.x;
    int v = (t < nt) ? counts[sb * nt + t] : 0;
    sdata[t] = v;
    __syncthreads();
    for (int off = 1; off < 512; off <<= 1) {
        int x = (t >= off) ? sdata[t - off] : 0;
        __syncthreads();
        sdata[t] += x;
        __syncthreads();
    }
    if (t < nt) tilebase[sb * nt + t] = sdata[t] - v;
    if (t == 511) sbtot[sb] = sdata[511];
}

// ---- scan pass 2: exclusive scan of the 98 sb totals ----
__global__ __launch_bounds__(128) void tscan2_kernel(const int* __restrict__ sbtot,
                                                     int* __restrict__ sbbase,
                                                     int n_edges) {
    __shared__ int sdata[128];
    int t = threadIdx.x;
    int v = (t < NSB) ? sbtot[t] : 0;
    sdata[t] = v;
    __syncthreads();
    for (int off = 1; off < 128; off <<= 1) {
        int x = (t >= off) ? sdata[t - off] : 0;
        __syncthreads();
        sdata[t] += x;
        __syncthreads();
    }
    if (t < NSB) sbbase[t] = sdata[t] - v;
    if (t == 0) sbbase[NSB] = n_edges;
}

// ---- partition: single pass, LDS cursors only (no global atomics) ----
__global__ __launch_bounds__(512) void partition_kernel(const int* __restrict__ src,
                                                        const int* __restrict__ dst,
                                                        int n_edges, int nt,
                                                        const int* __restrict__ tilebase,
                                                        const int* __restrict__ sbbase,
                                                        int* __restrict__ tmp) {
    __shared__ int lcur[NSB];
    int t = threadIdx.x;
    if (t < NSB) lcur[t] = sbbase[t] + tilebase[t * nt + blockIdx.x];
    __syncthreads();
    int s0 = blockIdx.x * ETILE;
    int s1 = s0 + ETILE; if (s1 > n_edges) s1 = n_edges;
    for (int e = s0 + t; e < s1; e += 512) {
        int d = dst[e];
        int sb = d >> SBSH;
        int ofs = atomicAdd(&lcur[sb], 1);
        tmp[ofs] = ((d & (SBN - 1)) << PACKSH) | src[e];
    }
}

// ---- per-superbucket counting sort: builds row_ptr + col_src (prescaled <<7) ----
__global__ __launch_bounds__(1024) void bucket_sort_kernel(
    const int* __restrict__ sbbase, const int* __restrict__ tmp,
    int* __restrict__ col_src, int* __restrict__ row_ptr,
    int n_nodes, int n_edges) {
    __shared__ int cnt[SBN];
    __shared__ int scan[SBN];
    int b = blockIdx.x, t = threadIdx.x;
    int gb = sbbase[b], ge = sbbase[b + 1];
    cnt[t] = 0;
    __syncthreads();
    for (int e = gb + t; e < ge; e += 1024)
        atomicAdd(&cnt[((unsigned)tmp[e]) >> PACKSH], 1);
    __syncthreads();
    int v = cnt[t];
    scan[t] = v;
    __syncthreads();
    for (int off = 1; off < 1024; off <<= 1) {
        int x = (t >= off) ? scan[t - off] : 0;
        __syncthreads();
        scan[t] += x;
        __syncthreads();
    }
    int excl = scan[t] - v;
    int node = (b << SBSH) + t;
    if (node < n_nodes) row_ptr[node] = gb + excl;
    cnt[t] = gb + excl;                       // reuse as cursor
    if (b == (int)gridDim.x - 1 && t == 0) row_ptr[n_nodes] = n_edges;
    __syncthreads();
    for (int e = gb + t; e < ge; e += 1024) {
        int pk = tmp[e];
        int pos = atomicAdd(&cnt[((unsigned)pk) >> PACKSH], 1);
        col_src[pos] = (pk & SRCMASK) << 7;   // byte offset of 128B bf16 row
    }
}

// ---- fp32 -> bf16 row conversion (8 elems/thread) ----
__global__ __launch_bounds__(256) void cvt_kernel(const float* __restrict__ x,
                                                  unsigned short* __restrict__ xb,
                                                  int n8) {
    int i = blockIdx.x * 256 + threadIdx.x;
    if (i >= n8) return;
    const float4* xp = (const float4*)x;
    float4 a = xp[2 * i], c = xp[2 * i + 1];
    int4 o;
    o.x = bf16_rne(a.x) | (bf16_rne(a.y) << 16);
    o.y = bf16_rne(a.z) | (bf16_rne(a.w) << 16);
    o.z = bf16_rne(c.x) | (bf16_rne(c.y) << 16);
    o.w = bf16_rne(c.z) | (bf16_rne(c.w) << 16);
    ((int4*)xb)[i] = o;
}

// ---- pack weights (fp32 64x64 k-major) into MFMA B-fragments, hi/lo bf16 split ----
__global__ __launch_bounds__(256) void wpack_kernel(
    const float* __restrict__ Wl1, const float* __restrict__ Wr1,
    const float* __restrict__ Wl2, const float* __restrict__ Wr2,
    unsigned short* __restrict__ wpack) {
    int u = blockIdx.x * 256 + threadIdx.x;   // 2048 units
    if (u >= 2048) return;
    int l = u & 63;
    int ct = (u >> 6) & 3;
    int chunk = (u >> 8) & 1;
    int gemm = (u >> 9) & 1;
    int layer = (u >> 10) & 1;
    const float* W = layer ? (gemm ? Wr2 : Wl2) : (gemm ? Wr1 : Wl1);
    int col = ct * 16 + (l & 15);
    int k0 = chunk * 32 + (l >> 4) * 8;
    unsigned hi[8], lo[8];
#pragma unroll
    for (int j = 0; j < 8; ++j) {
        float w = W[(k0 + j) * DFEAT + col];
        unsigned h = bf16_rne(w);
        float whi = __uint_as_float(h << 16);
        lo[j] = bf16_rne(w - whi);
        hi[j] = h;
    }
    size_t fh = ((((size_t)(layer * 2 + gemm) * 2 + 0) * 2 + chunk) * 4 + ct) * 64 + l;
    size_t fl = ((((size_t)(layer * 2 + gemm) * 2 + 1) * 2 + chunk) * 4 + ct) * 64 + l;
    int4 vh, vl;
    vh.x = hi[0] | (hi[1] << 16); vh.y = hi[2] | (hi[3] << 16);
    vh.z = hi[4] | (hi[5] << 16); vh.w = hi[6] | (hi[7] << 16);
    vl.x = lo[0] | (lo[1] << 16); vl.y = lo[2] | (lo[3] << 16);
    vl.z = lo[4] | (lo[5] << 16); vl.w = lo[6] | (lo[7] << 16);
    ((int4*)wpack)[fh] = vh;
    ((int4*)wpack)[fl] = vl;
}

// ---- gather-mean aggregation (bf16 rows): wave=node, 8 lanes/row, 8 rows/load ----
__global__ __launch_bounds__(512, 8) void agg_kernel(
    const int* __restrict__ row_ptr, const int* __restrict__ col_src,
    const unsigned short* __restrict__ xb, unsigned short* __restrict__ meanb,
    int n_nodes) {
    int w = threadIdx.x >> 6;
    int lane = threadIdx.x & 63;
    int g = lane >> 3;            // row-group 0..7
    int p = lane & 7;             // 16B slot within 128B row
    int node = blockIdx.x * 8 + w;
    if (node >= n_nodes) return;  // no barriers in this kernel

    int start = row_ptr[node];
    int end = row_ptr[node + 1];
    int deg = end - start;

    float acc[8] = {0.f, 0.f, 0.f, 0.f, 0.f, 0.f, 0.f, 0.f};
    const char* xbase = (const char*)xb + p * 16;

    for (int base = start; base < end; base += 64) {
        int m = end - base; if (m > 64) m = 64;
        int soff = col_src[base + (lane < m ? lane : 0)];
        for (int i = 0; i < m; i += 32) {
#pragma unroll
            for (int k = 0; k < 4; ++k) {
                if (i + 8 * k < m) {                       // wave-uniform
                    int n = i + 8 * k + g;
                    int off = __shfl(soff, n < m ? n : 0);
                    float f = (n < m) ? 1.0f : 0.0f;
                    int4 v = *(const int4*)(xbase + off);
                    acc[0] += f * __uint_as_float(((unsigned)v.x) << 16);
                    acc[1] += f * __uint_as_float(((unsigned)v.x) & 0xFFFF0000u);
                    acc[2] += f * __uint_as_float(((unsigned)v.y) << 16);
                    acc[3] += f * __uint_as_float(((unsigned)v.y) & 0xFFFF0000u);
                    acc[4] += f * __uint_as_float(((unsigned)v.z) << 16);
                    acc[5] += f * __uint_as_float(((unsigned)v.z) & 0xFFFF0000u);
                    acc[6] += f * __uint_as_float(((unsigned)v.w) << 16);
                    acc[7] += f * __uint_as_float(((unsigned)v.w) & 0xFFFF0000u);
                }
            }
        }
    }

#pragma unroll
    for (int d = 8; d < 64; d <<= 1) {
#pragma unroll
        for (int e = 0; e < 8; ++e) acc[e] += __shfl_xor(acc[e], d);
    }

    if (g == 0) {
        float inv = (deg > 0) ? 1.0f / (float)deg : 0.0f;
        unsigned u[8];
#pragma unroll
        for (int e = 0; e < 8; ++e) u[e] = bf16_rne(acc[e] * inv);
        int4 o;
        o.x = u[0] | (u[1] << 16);
        o.y = u[2] | (u[3] << 16);
        o.z = u[4] | (u[5] << 16);
        o.w = u[6] | (u[7] << 16);
        *(int4*)((char*)meanb + (size_t)node * 128 + p * 16) = o;
    }
}

// ---- MFMA linear: out[16n x 64] = [A|X] @ [Wl;Wr] + b ; one wave per 16-node tile ----
template <bool RELU, bool OUT_BF16>
__global__ __launch_bounds__(256) void linear_kernel(
    const unsigned short* __restrict__ Ab, const unsigned short* __restrict__ Xb,
    const unsigned short* __restrict__ wpack,   // layer-offset applied by caller
    const float* __restrict__ bias, void* __restrict__ outp,
    int n_nodes, int ntiles) {
    int wave = (blockIdx.x * 256 + threadIdx.x) >> 6;
    if (wave >= ntiles) return;
    int l = threadIdx.x & 63;
    int row16 = l & 15;
    int kq = l >> 4;
    int node0 = wave * 16;

    int arow = node0 + row16;
    if (arow >= n_nodes) arow = n_nodes - 1;
    const char* ap = (const char*)Ab + (size_t)arow * 128 + kq * 16;
    const char* xp = (const char*)Xb + (size_t)arow * 128 + kq * 16;
    bf16x8 aA0 = *(const bf16x8*)ap;
    bf16x8 aA1 = *(const bf16x8*)(ap + 64);
    bf16x8 aX0 = *(const bf16x8*)xp;
    bf16x8 aX1 = *(const bf16x8*)(xp + 64);

    const bf16x8* wp = (const bf16x8*)wpack;
#pragma unroll
    for (int ct = 0; ct < 4; ++ct) {
        float bcol = bias[ct * 16 + row16];
        f32x4 acc = {bcol, bcol, bcol, bcol};
        bf16x8 b000 = wp[0 * 256 + ct * 64 + l];   // A, hi, c0
        bf16x8 b001 = wp[1 * 256 + ct * 64 + l];   // A, hi, c1
        bf16x8 b010 = wp[2 * 256 + ct * 64 + l];   // A, lo, c0
        bf16x8 b011 = wp[3 * 256 + ct * 64 + l];   // A, lo, c1
        bf16x8 b100 = wp[4 * 256 + ct * 64 + l];   // X, hi, c0
        bf16x8 b101 = wp[5 * 256 + ct * 64 + l];   // X, hi, c1
        bf16x8 b110 = wp[6 * 256 + ct * 64 + l];   // X, lo, c0
        bf16x8 b111 = wp[7 * 256 + ct * 64 + l];   // X, lo, c1
        acc = __builtin_amdgcn_mfma_f32_16x16x32_bf16(aA0, b000, acc, 0, 0, 0);
        acc = __builtin_amdgcn_mfma_f32_16x16x32_bf16(aA1, b001, acc, 0, 0, 0);
        acc = __builtin_amdgcn_mfma_f32_16x16x32_bf16(aA0, b010, acc, 0, 0, 0);
        acc = __builtin_amdgcn_mfma_f32_16x16x32_bf16(aA1, b011, acc, 0, 0, 0);
        acc = __builtin_amdgcn_mfma_f32_16x16x32_bf16(aX0, b100, acc, 0, 0, 0);
        acc = __builtin_amdgcn_mfma_f32_16x16x32_bf16(aX1, b101, acc, 0, 0, 0);
        acc = __builtin_amdgcn_mfma_f32_16x16x32_bf16(aX0, b110, acc, 0, 0, 0);
        acc = __builtin_amdgcn_mfma_f32_16x16x32_bf16(aX1, b111, acc, 0, 0, 0);
#pragma unroll
        for (int reg = 0; reg < 4; ++reg) {
            int row = kq * 4 + reg;                // C/D: row=(lane>>4)*4+reg
            int gn = node0 + row;
            if (gn < n_nodes) {
                float v = acc[reg];
                if (RELU) v = fmaxf(v, 0.0f);
                if (OUT_BF16) {
                    ((unsigned short*)outp)[(size_t)gn * DFEAT + ct * 16 + row16] =
                        (unsigned short)bf16_rne(v);
                } else {
                    ((float*)outp)[(size_t)gn * DFEAT + ct * 16 + row16] = v;
                }
            }
        }
    }
}

extern "C" void kernel_launch(void* const* d_in, const int* in_sizes, int n_in,
                              void* d_out, int out_size, void* d_ws, size_t ws_size,
                              hipStream_t stream) {
    const float* x   = (const float*)d_in[0];
    const int*   ei  = (const int*)d_in[1];
    const float* Wl1 = (const float*)d_in[2];
    const float* Wr1 = (const float*)d_in[3];
    const float* b1  = (const float*)d_in[4];
    const float* Wl2 = (const float*)d_in[5];
    const float* Wr2 = (const float*)d_in[6];
    const float* b2  = (const float*)d_in[7];
    float* out = (float*)d_out;

    int n_nodes = in_sizes[0] / DFEAT;   // 100000
    int n_edges = in_sizes[1] / 2;       // 1600000
    const int* src  = ei;
    const int* dstv = ei + n_edges;
    int nt = (n_edges + ETILE - 1) / ETILE;   // 391 (must be <= 512)

    auto align = [](size_t v) { return (v + 255) & ~(size_t)255; };
    char* ws = (char*)d_ws;
    int* counts   = (int*)ws;            ws += align((size_t)NSB * nt * 4);      // 153KB
    int* tilebase = (int*)ws;            ws += align((size_t)NSB * nt * 4);      // 153KB
    int* sbtot    = (int*)ws;            ws += align(NSB * 4);
    int* sbbase   = (int*)ws;            ws += align((NSB + 1) * 4);
    int* row_ptr  = (int*)ws;            ws += align(((size_t)n_nodes + 1) * 4);
    int* col_src  = (int*)ws;            ws += align((size_t)n_edges * 4);       // 6.4MB
    unsigned short* xb    = (unsigned short*)ws; ws += align((size_t)n_nodes * DFEAT * 2);
    unsigned short* hb    = (unsigned short*)ws; ws += align((size_t)n_nodes * DFEAT * 2);
    unsigned short* meanb = (unsigned short*)ws; ws += align((size_t)n_nodes * DFEAT * 2);
    unsigned short* wpack = (unsigned short*)ws; ws += align((size_t)32768);
    int* tmp      = (int*)d_out;         // 6.4MB, dead until linear2 writes out

    bhist_kernel<<<nt, 512, 0, stream>>>(dstv, n_edges, nt, counts);
    tscan1_kernel<<<NSB, 512, 0, stream>>>(counts, nt, tilebase, sbtot);
    tscan2_kernel<<<1, 128, 0, stream>>>(sbtot, sbbase, n_edges);
    partition_kernel<<<nt, 512, 0, stream>>>(src, dstv, n_edges, nt, tilebase,
                                             sbbase, tmp);
    bucket_sort_kernel<<<NSB, 1024, 0, stream>>>(sbbase, tmp, col_src, row_ptr,
                                                 n_nodes, n_edges);

    int n8 = n_nodes * DFEAT / 8;
    cvt_kernel<<<(n8 + 255) / 256, 256, 0, stream>>>(x, xb, n8);
    wpack_kernel<<<8, 256, 0, stream>>>(Wl1, Wr1, Wl2, Wr2, wpack);

    int ntiles = (n_nodes + 15) / 16;    // 6250
    int nb = (n_nodes + 7) / 8;          // 12500
    int lb = (ntiles + 3) / 4;           // 1563 blocks (4 waves each)

    agg_kernel<<<nb, 512, 0, stream>>>(row_ptr, col_src, xb, meanb, n_nodes);
    linear_kernel<true, true><<<lb, 256, 0, stream>>>(meanb, xb, wpack, b1,
                                                      hb, n_nodes, ntiles);
    agg_kernel<<<nb, 512, 0, stream>>>(row_ptr, col_src, hb, meanb, n_nodes);
    linear_kernel<false, false><<<lb, 256, 0, stream>>>(meanb, hb, wpack + 2048 * 8,
                                                        b2, out, n_nodes, ntiles);
}

// Round 11
// 151.517 us; speedup vs baseline: 1.6568x; 1.1195x over previous
//
#include <hip/hip_runtime.h>

#define DFEAT 64
#define SBSH 10
#define SBN 1024                  // nodes per superbucket
#define NSB 98                    // ceil(100000/1024)
#define ETILE 4096
#define PACKSH 17
#define SRCMASK 0x1FFFF

typedef __bf16 bf16x8 __attribute__((ext_vector_type(8)));
typedef float f32x4 __attribute__((ext_vector_type(4)));

__device__ __forceinline__ unsigned bf16_rne(float v) {
    unsigned bits = __float_as_uint(v);
    return (bits + 0x7FFFu + ((bits >> 16) & 1u)) >> 16;
}
__device__ __forceinline__ float lo16(unsigned u) { return __uint_as_float(u << 16); }
__device__ __forceinline__ float hi16(unsigned u) { return __uint_as_float(u & 0xFFFF0000u); }

// ---- merged setup: bhist tiles | wpack | cvt, role by blockIdx ----
__global__ __launch_bounds__(512) void setup_kernel(
    const int* __restrict__ dst, int n_edges, int nt, int* __restrict__ counts,
    const float* __restrict__ x, unsigned short* __restrict__ xb, int ncvt,
    const float* __restrict__ Wl1, const float* __restrict__ Wr1,
    const float* __restrict__ Wl2, const float* __restrict__ Wr2,
    unsigned short* __restrict__ wpack) {
    int b = blockIdx.x, t = threadIdx.x;
    if (b < nt) {
        __shared__ int lh[NSB];
        if (t < NSB) lh[t] = 0;
        __syncthreads();
        int s0 = b * ETILE;
        int s1 = s0 + ETILE; if (s1 > n_edges) s1 = n_edges;
        for (int e = s0 + t; e < s1; e += 512)
            atomicAdd(&lh[dst[e] >> SBSH], 1);
        __syncthreads();
        if (t < NSB) counts[t * nt + b] = lh[t];
    } else if (b < nt + 4) {
        int u = (b - nt) * 512 + t;          // 0..2047
        int l = u & 63;
        int ct = (u >> 6) & 3;
        int chunk = (u >> 8) & 1;
        int gemm = (u >> 9) & 1;
        int layer = (u >> 10) & 1;
        const float* W = layer ? (gemm ? Wr2 : Wl2) : (gemm ? Wr1 : Wl1);
        int col = ct * 16 + (l & 15);
        int k0 = chunk * 32 + (l >> 4) * 8;
        unsigned hi[8], lo[8];
#pragma unroll
        for (int j = 0; j < 8; ++j) {
            float w = W[(k0 + j) * DFEAT + col];
            unsigned h = bf16_rne(w);
            float whi = __uint_as_float(h << 16);
            lo[j] = bf16_rne(w - whi);
            hi[j] = h;
        }
        size_t fh = ((((size_t)(layer * 2 + gemm) * 2 + 0) * 2 + chunk) * 4 + ct) * 64 + l;
        size_t fl = ((((size_t)(layer * 2 + gemm) * 2 + 1) * 2 + chunk) * 4 + ct) * 64 + l;
        int4 vh, vl;
        vh.x = hi[0] | (hi[1] << 16); vh.y = hi[2] | (hi[3] << 16);
        vh.z = hi[4] | (hi[5] << 16); vh.w = hi[6] | (hi[7] << 16);
        vl.x = lo[0] | (lo[1] << 16); vl.y = lo[2] | (lo[3] << 16);
        vl.z = lo[4] | (lo[5] << 16); vl.w = lo[6] | (lo[7] << 16);
        ((int4*)wpack)[fh] = vh;
        ((int4*)wpack)[fl] = vl;
    } else {
        int i = (b - nt - 4) * 512 + t;
        if (i < ncvt) {
            const float4* xp = (const float4*)x;
            float4 a = xp[2 * i], c = xp[2 * i + 1];
            int4 o;
            o.x = bf16_rne(a.x) | (bf16_rne(a.y) << 16);
            o.y = bf16_rne(a.z) | (bf16_rne(a.w) << 16);
            o.z = bf16_rne(c.x) | (bf16_rne(c.y) << 16);
            o.w = bf16_rne(c.z) | (bf16_rne(c.w) << 16);
            ((int4*)xb)[i] = o;
        }
    }
}

// ---- scan pass 1: per-sb exclusive scan over its nt tile-counts ----
__global__ __launch_bounds__(512) void tscan1_kernel(const int* __restrict__ counts,
                                                     int nt,
                                                     int* __restrict__ tilebase,
                                                     int* __restrict__ sbtot) {
    __shared__ int sdata[512];
    int sb = blockIdx.x, t = threadIdx.x;
    int v = (t < nt) ? counts[sb * nt + t] : 0;
    sdata[t] = v;
    __syncthreads();
    for (int off = 1; off < 512; off <<= 1) {
        int x = (t >= off) ? sdata[t - off] : 0;
        __syncthreads();
        sdata[t] += x;
        __syncthreads();
    }
    if (t < nt) tilebase[sb * nt + t] = sdata[t] - v;
    if (t == 511) sbtot[sb] = sdata[511];
}

// ---- scan pass 2: exclusive scan of the 98 sb totals ----
__global__ __launch_bounds__(128) void tscan2_kernel(const int* __restrict__ sbtot,
                                                     int* __restrict__ sbbase,
                                                     int n_edges) {
    __shared__ int sdata[128];
    int t = threadIdx.x;
    int v = (t < NSB) ? sbtot[t] : 0;
    sdata[t] = v;
    __syncthreads();
    for (int off = 1; off < 128; off <<= 1) {
        int x = (t >= off) ? sdata[t - off] : 0;
        __syncthreads();
        sdata[t] += x;
        __syncthreads();
    }
    if (t < NSB) sbbase[t] = sdata[t] - v;
    if (t == 0) sbbase[NSB] = n_edges;
}

// ---- partition: single pass, LDS cursors only ----
__global__ __launch_bounds__(512) void partition_kernel(const int* __restrict__ src,
                                                        const int* __restrict__ dst,
                                                        int n_edges, int nt,
                                                        const int* __restrict__ tilebase,
                                                        const int* __restrict__ sbbase,
                                                        int* __restrict__ tmp) {
    __shared__ int lcur[NSB];
    int t = threadIdx.x;
    if (t < NSB) lcur[t] = sbbase[t] + tilebase[t * nt + blockIdx.x];
    __syncthreads();
    int s0 = blockIdx.x * ETILE;
    int s1 = s0 + ETILE; if (s1 > n_edges) s1 = n_edges;
    for (int e = s0 + t; e < s1; e += 512) {
        int d = dst[e];
        int sb = d >> SBSH;
        int ofs = atomicAdd(&lcur[sb], 1);
        tmp[ofs] = ((d & (SBN - 1)) << PACKSH) | src[e];
    }
}

// ---- per-superbucket counting sort: builds row_ptr + col_src (prescaled <<7) ----
__global__ __launch_bounds__(1024) void bucket_sort_kernel(
    const int* __restrict__ sbbase, const int* __restrict__ tmp,
    int* __restrict__ col_src, int* __restrict__ row_ptr,
    int n_nodes, int n_edges) {
    __shared__ int cnt[SBN];
    __shared__ int scan[SBN];
    int b = blockIdx.x, t = threadIdx.x;
    int gb = sbbase[b], ge = sbbase[b + 1];
    cnt[t] = 0;
    __syncthreads();
    for (int e = gb + t; e < ge; e += 1024)
        atomicAdd(&cnt[((unsigned)tmp[e]) >> PACKSH], 1);
    __syncthreads();
    int v = cnt[t];
    scan[t] = v;
    __syncthreads();
    for (int off = 1; off < 1024; off <<= 1) {
        int x = (t >= off) ? scan[t - off] : 0;
        __syncthreads();
        scan[t] += x;
        __syncthreads();
    }
    int excl = scan[t] - v;
    int node = (b << SBSH) + t;
    if (node < n_nodes) row_ptr[node] = gb + excl;
    cnt[t] = gb + excl;                       // reuse as cursor
    if (b == (int)gridDim.x - 1 && t == 0) row_ptr[n_nodes] = n_edges;
    __syncthreads();
    for (int e = gb + t; e < ge; e += 1024) {
        int pk = tmp[e];
        int pos = atomicAdd(&cnt[((unsigned)pk) >> PACKSH], 1);
        col_src[pos] = (pk & SRCMASK) << 7;   // byte offset of 128B bf16 row
    }
}

// ---- fused SAGE layer: gather-mean (2 nodes/wave, 16 lanes/row) + MFMA linear ----
// block = 512 thr = 8 waves = one 16-node tile; wave w aggregates rows w and w+8
template <bool RELU, bool OUT_BF16>
__global__ __launch_bounds__(512, 4) void sage_kernel(
    const int* __restrict__ row_ptr, const int* __restrict__ col_src,
    const unsigned short* __restrict__ xb,
    const unsigned short* __restrict__ wpk,   // this layer's fragments
    const float* __restrict__ bias, void* __restrict__ outp, int n_nodes) {
    __shared__ unsigned short sMean[16 * 72];   // 72-short (144B) stride
    int t = threadIdx.x;
    int w = t >> 6;
    int lane = t & 63;
    int g4 = lane >> 4;           // row-group 0..3
    int p4 = lane & 15;           // 8B slot within 128B row
    int node0 = blockIdx.x * 16;
    const char* xb8 = (const char*)xb + p4 * 8;

    int nA = node0 + w;
    int nB = node0 + w + 8;
    int ncA = nA < n_nodes ? nA : n_nodes - 1;
    int ncB = nB < n_nodes ? nB : n_nodes - 1;
    int baseA = row_ptr[ncA], endA = row_ptr[ncA + 1];
    int baseB = row_ptr[ncB], endB = row_ptr[ncB + 1];
    int degA = endA - baseA, degB = endB - baseB;

    float accA[4] = {0.f, 0.f, 0.f, 0.f};
    float accB[4] = {0.f, 0.f, 0.f, 0.f};

    while (baseA < endA || baseB < endB) {
        int mA = endA - baseA; if (mA > 64) mA = 64; if (mA < 0) mA = 0;
        int mB = endB - baseB; if (mB > 64) mB = 64; if (mB < 0) mB = 0;
        int soffA = mA > 0 ? col_src[baseA + (lane < mA ? lane : 0)] : 0;
        int soffB = mB > 0 ? col_src[baseB + (lane < mB ? lane : 0)] : 0;
        int mmax = mA > mB ? mA : mB;
        for (int i = 0; i < mmax; i += 16) {
#pragma unroll
            for (int k = 0; k < 4; ++k) {
                int base4 = i + 4 * k;
                int n = base4 + g4;
                if (base4 < mA) {                      // wave-uniform
                    int off = __shfl(soffA, n < mA ? n : 0);
                    float f = (n < mA) ? 1.f : 0.f;
                    int2 v = *(const int2*)(xb8 + off);
                    accA[0] += f * lo16((unsigned)v.x);
                    accA[1] += f * hi16((unsigned)v.x);
                    accA[2] += f * lo16((unsigned)v.y);
                    accA[3] += f * hi16((unsigned)v.y);
                }
                if (base4 < mB) {
                    int off = __shfl(soffB, n < mB ? n : 0);
                    float f = (n < mB) ? 1.f : 0.f;
                    int2 v = *(const int2*)(xb8 + off);
                    accB[0] += f * lo16((unsigned)v.x);
                    accB[1] += f * hi16((unsigned)v.x);
                    accB[2] += f * lo16((unsigned)v.y);
                    accB[3] += f * hi16((unsigned)v.y);
                }
            }
        }
        baseA += 64;
        baseB += 64;
    }

#pragma unroll
    for (int e = 0; e < 4; ++e) {
        accA[e] += __shfl_xor(accA[e], 16); accA[e] += __shfl_xor(accA[e], 32);
        accB[e] += __shfl_xor(accB[e], 16); accB[e] += __shfl_xor(accB[e], 32);
    }

    if (g4 == 0) {
        float invA = degA > 0 ? 1.f / (float)degA : 0.f;
        float invB = degB > 0 ? 1.f / (float)degB : 0.f;
        int2 oA, oB;
        oA.x = bf16_rne(accA[0] * invA) | (bf16_rne(accA[1] * invA) << 16);
        oA.y = bf16_rne(accA[2] * invA) | (bf16_rne(accA[3] * invA) << 16);
        oB.x = bf16_rne(accB[0] * invB) | (bf16_rne(accB[1] * invB) << 16);
        oB.y = bf16_rne(accB[2] * invB) | (bf16_rne(accB[3] * invB) << 16);
        *(int2*)&sMean[w * 72 + p4 * 4] = oA;
        *(int2*)&sMean[(w + 8) * 72 + p4 * 4] = oB;
    }
    __syncthreads();

    // ---- MFMA linear phase: waves 0..3, ct = w ----
    if (w < 4) {
        int ct = w;
        int row16 = lane & 15;
        int kq = lane >> 4;
        bf16x8 aA0 = *(const bf16x8*)&sMean[row16 * 72 + kq * 8];
        bf16x8 aA1 = *(const bf16x8*)&sMean[row16 * 72 + 32 + kq * 8];
        int xr = node0 + row16; if (xr >= n_nodes) xr = n_nodes - 1;
        const char* xp = (const char*)xb + (size_t)xr * 128 + kq * 16;
        bf16x8 aX0 = *(const bf16x8*)xp;
        bf16x8 aX1 = *(const bf16x8*)(xp + 64);

        const bf16x8* wp = (const bf16x8*)wpk;
        float bcol = bias[ct * 16 + row16];
        f32x4 acc = {bcol, bcol, bcol, bcol};
        acc = __builtin_amdgcn_mfma_f32_16x16x32_bf16(aA0, wp[0 * 256 + ct * 64 + lane], acc, 0, 0, 0);
        acc = __builtin_amdgcn_mfma_f32_16x16x32_bf16(aA1, wp[1 * 256 + ct * 64 + lane], acc, 0, 0, 0);
        acc = __builtin_amdgcn_mfma_f32_16x16x32_bf16(aA0, wp[2 * 256 + ct * 64 + lane], acc, 0, 0, 0);
        acc = __builtin_amdgcn_mfma_f32_16x16x32_bf16(aA1, wp[3 * 256 + ct * 64 + lane], acc, 0, 0, 0);
        acc = __builtin_amdgcn_mfma_f32_16x16x32_bf16(aX0, wp[4 * 256 + ct * 64 + lane], acc, 0, 0, 0);
        acc = __builtin_amdgcn_mfma_f32_16x16x32_bf16(aX1, wp[5 * 256 + ct * 64 + lane], acc, 0, 0, 0);
        acc = __builtin_amdgcn_mfma_f32_16x16x32_bf16(aX0, wp[6 * 256 + ct * 64 + lane], acc, 0, 0, 0);
        acc = __builtin_amdgcn_mfma_f32_16x16x32_bf16(aX1, wp[7 * 256 + ct * 64 + lane], acc, 0, 0, 0);
#pragma unroll
        for (int reg = 0; reg < 4; ++reg) {
            int row = kq * 4 + reg;               // C/D: row=(lane>>4)*4+reg
            int gn = node0 + row;
            if (gn < n_nodes) {
                float v = acc[reg];
                if (RELU) v = fmaxf(v, 0.0f);
                if (OUT_BF16) {
                    ((unsigned short*)outp)[(size_t)gn * DFEAT + ct * 16 + row16] =
                        (unsigned short)bf16_rne(v);
                } else {
                    ((float*)outp)[(size_t)gn * DFEAT + ct * 16 + row16] = v;
                }
            }
        }
    }
}

extern "C" void kernel_launch(void* const* d_in, const int* in_sizes, int n_in,
                              void* d_out, int out_size, void* d_ws, size_t ws_size,
                              hipStream_t stream) {
    const float* x   = (const float*)d_in[0];
    const int*   ei  = (const int*)d_in[1];
    const float* Wl1 = (const float*)d_in[2];
    const float* Wr1 = (const float*)d_in[3];
    const float* b1  = (const float*)d_in[4];
    const float* Wl2 = (const float*)d_in[5];
    const float* Wr2 = (const float*)d_in[6];
    const float* b2  = (const float*)d_in[7];
    float* out = (float*)d_out;

    int n_nodes = in_sizes[0] / DFEAT;   // 100000
    int n_edges = in_sizes[1] / 2;       // 1600000
    const int* src  = ei;
    const int* dstv = ei + n_edges;
    int nt = (n_edges + ETILE - 1) / ETILE;   // 391 (<= 512 for tscan1)

    auto align = [](size_t v) { return (v + 255) & ~(size_t)255; };
    char* ws = (char*)d_ws;
    int* counts   = (int*)ws;            ws += align((size_t)NSB * nt * 4);
    int* tilebase = (int*)ws;            ws += align((size_t)NSB * nt * 4);
    int* sbtot    = (int*)ws;            ws += align(NSB * 4);
    int* sbbase   = (int*)ws;            ws += align((NSB + 1) * 4);
    int* row_ptr  = (int*)ws;            ws += align(((size_t)n_nodes + 1) * 4);
    int* col_src  = (int*)ws;            ws += align((size_t)n_edges * 4);
    unsigned short* xb    = (unsigned short*)ws; ws += align((size_t)n_nodes * DFEAT * 2);
    unsigned short* hb    = (unsigned short*)ws; ws += align((size_t)n_nodes * DFEAT * 2);
    unsigned short* wpack = (unsigned short*)ws; ws += align((size_t)32768);
    int* tmp      = (int*)d_out;         // 6.4MB, dead before sage2 writes out

    int ncvt = n_nodes * DFEAT / 8;                 // 800000 int4-units
    int cvtb = (ncvt + 511) / 512;                  // 1563
    setup_kernel<<<nt + 4 + cvtb, 512, 0, stream>>>(dstv, n_edges, nt, counts,
                                                    x, xb, ncvt,
                                                    Wl1, Wr1, Wl2, Wr2, wpack);
    tscan1_kernel<<<NSB, 512, 0, stream>>>(counts, nt, tilebase, sbtot);
    tscan2_kernel<<<1, 128, 0, stream>>>(sbtot, sbbase, n_edges);
    partition_kernel<<<nt, 512, 0, stream>>>(src, dstv, n_edges, nt, tilebase,
                                             sbbase, tmp);
    bucket_sort_kernel<<<NSB, 1024, 0, stream>>>(sbbase, tmp, col_src, row_ptr,
                                                 n_nodes, n_edges);

    int tiles = (n_nodes + 15) / 16;     // 6250 blocks
    sage_kernel<true, true><<<tiles, 512, 0, stream>>>(row_ptr, col_src, xb,
                                                       wpack, b1, hb, n_nodes);
    sage_kernel<false, false><<<tiles, 512, 0, stream>>>(row_ptr, col_src, hb,
                                                         wpack + 2048 * 8, b2,
                                                         out, n_nodes);
}